// Round 1
// baseline (179.100 us; speedup 1.0000x reference)
//
#include <hip/hip_runtime.h>
#include <math.h>

// Problem shape (fixed by the harness/reference):
#define BB 8
#define NN 8192
#define MM 8192
// D = 3

// d_ws layout:
//   [0..1]   float accumulators: [0]=sum_g2p, [1]=sum_p2g
//   +64B     unsigned int minp[BB*MM]  (uint-bit float mins, all values >= 0)

__global__ void chamfer_init(unsigned int* __restrict__ minp,
                             float* __restrict__ accum) {
    int idx = blockIdx.x * blockDim.x + threadIdx.x;
    if (idx < BB * MM) minp[idx] = 0x7F800000u;   // +inf
    if (idx < 2) accum[idx] = 0.0f;
}

// Block: 256 threads = 16x16 (tx,ty). Block owns 128 gt rows (8 per ty),
// loops over all M preds in 128-wide LDS chunks (8 per tx, stride 16).
__global__ __launch_bounds__(256) void chamfer_main(
    const float* __restrict__ gts, const float* __restrict__ preds,
    unsigned int* __restrict__ minp, float* __restrict__ accum)
{
    __shared__ float4 sp[128];        // pred chunk: x,y,z, -0.5*|p|^2
    __shared__ float sm2[4][128];     // cross-wave col-min merge

    const int b = blockIdx.y;
    const int rowBase = blockIdx.x * 128;
    const int tid  = threadIdx.x;
    const int tx   = tid & 15;
    const int ty   = tid >> 4;
    const int lane = tid & 63;
    const int wave = tid >> 6;

    const float kInf = __builtin_inff();

    // Load this thread's 8 gt points into registers; precompute |a|^2.
    float ax[8], ay[8], az[8], aw[8], rm[8];
    const float* gbase = gts + ((size_t)b * NN + rowBase + ty * 8) * 3;
#pragma unroll
    for (int g = 0; g < 8; ++g) {
        float x = gbase[g * 3 + 0];
        float y = gbase[g * 3 + 1];
        float z = gbase[g * 3 + 2];
        ax[g] = x; ay[g] = y; az[g] = z;
        aw[g] = x * x + y * y + z * z;
        rm[g] = kInf;
    }

    const float* pbase = preds + (size_t)b * MM * 3;
    unsigned int* minp_b = minp + (size_t)b * MM;

    for (int c0 = 0; c0 < MM; c0 += 128) {
        __syncthreads();   // protect sp & sm2 from previous iteration's readers
        if (tid < 128) {
            const float* p = pbase + (size_t)(c0 + tid) * 3;
            float x = p[0], y = p[1], z = p[2];
            sp[tid] = make_float4(x, y, z, -0.5f * (x * x + y * y + z * z));
        }
        __syncthreads();

        float cm[8];
#pragma unroll
        for (int k = 0; k < 8; ++k) cm[k] = kInf;

#pragma unroll
        for (int k = 0; k < 8; ++k) {
            float4 p = sp[tx + 16 * k];   // 2-way LDS aliasing max (free)
#pragma unroll
            for (int g = 0; g < 8; ++g) {
                // d2 = |a|^2 + |p|^2 - 2 a.p   (matches reference formula)
                float t = fmaf(ax[g], p.x,
                          fmaf(ay[g], p.y,
                          fmaf(az[g], p.z, p.w)));     // t = a.p - |p|^2/2
                float d = fmaf(-2.0f, t, aw[g]);
                rm[g] = fminf(rm[g], d);
                cm[k] = fminf(cm[k], d);
            }
        }

        // Reduce col-mins across ty within each wave (lane bits 4,5 = ty&3).
#pragma unroll
        for (int k = 0; k < 8; ++k) {
            float v = cm[k];
            v = fminf(v, __shfl_xor(v, 16, 64));
            v = fminf(v, __shfl_xor(v, 32, 64));
            cm[k] = v;
        }
        if (lane < 16) {   // one ty-group leader per wave; tx == lane
#pragma unroll
            for (int k = 0; k < 8; ++k) sm2[wave][lane + 16 * k] = cm[k];
        }
        __syncthreads();
        if (tid < 128) {
            float v = fminf(fminf(sm2[0][tid], sm2[1][tid]),
                            fminf(sm2[2][tid], sm2[3][tid]));
            v = fmaxf(v, 0.0f);   // clamp (reference clamps before min; min/commute)
            atomicMin(&minp_b[c0 + tid], __float_as_uint(v));
        }
    }

    // Row mins are final for this block: reduce across tx (lane bits 0..3),
    // clamp, sum the block's 128 rows, one atomicAdd per ty-leader.
    float s = 0.0f;
#pragma unroll
    for (int g = 0; g < 8; ++g) {
        float v = rm[g];
        v = fminf(v, __shfl_xor(v, 1, 64));
        v = fminf(v, __shfl_xor(v, 2, 64));
        v = fminf(v, __shfl_xor(v, 4, 64));
        v = fminf(v, __shfl_xor(v, 8, 64));
        s += fmaxf(v, 0.0f);
    }
    if (tx == 0) atomicAdd(&accum[0], s);
}

__global__ void chamfer_reduce(const unsigned int* __restrict__ minp,
                               float* __restrict__ accum) {
    int idx = blockIdx.x * blockDim.x + threadIdx.x;
    float s = 0.0f;
    for (int i = idx; i < BB * MM; i += gridDim.x * blockDim.x)
        s += __uint_as_float(minp[i]);
#pragma unroll
    for (int m = 1; m < 64; m <<= 1) s += __shfl_xor(s, m, 64);
    __shared__ float wsum[4];
    if ((threadIdx.x & 63) == 0) wsum[threadIdx.x >> 6] = s;
    __syncthreads();
    if (threadIdx.x == 0)
        atomicAdd(&accum[1], wsum[0] + wsum[1] + wsum[2] + wsum[3]);
}

__global__ void chamfer_finalize(const float* __restrict__ accum,
                                 float* __restrict__ out) {
    out[0] = accum[0] / (float)((size_t)BB * NN)
           + accum[1] / (float)((size_t)BB * MM);
}

extern "C" void kernel_launch(void* const* d_in, const int* in_sizes, int n_in,
                              void* d_out, int out_size, void* d_ws, size_t ws_size,
                              hipStream_t stream) {
    const float* gts   = (const float*)d_in[0];
    const float* preds = (const float*)d_in[1];
    float* out = (float*)d_out;

    float* accum = (float*)d_ws;
    unsigned int* minp = (unsigned int*)((char*)d_ws + 64);

    chamfer_init<<<(BB * MM + 255) / 256, 256, 0, stream>>>(minp, accum);

    dim3 grid(NN / 128, BB);
    chamfer_main<<<grid, 256, 0, stream>>>(gts, preds, minp, accum);

    chamfer_reduce<<<64, 256, 0, stream>>>(minp, accum);
    chamfer_finalize<<<1, 1, 0, stream>>>(accum, out);
}